// Round 11
// baseline (189.006 us; speedup 1.0000x reference)
//
#include <hip/hip_runtime.h>
#include <math.h>

#define WAY   32
#define QUERY 128
#define FEAT  640
#define NPAIR 992
#define WQ    4096
#define NPROD 310    // producer blocks (31 p-tiles x 10 o-tiles)
#define NCONS 512    // consumer blocks (256 q-tiles x 2 wi-halves)

typedef short bf16x8  __attribute__((ext_vector_type(8)));
typedef short short4v __attribute__((ext_vector_type(4)));
typedef float f32x4   __attribute__((ext_vector_type(4)));

static __device__ __forceinline__ float leaky(float v) {
    return v >= 0.0f ? v : 0.2f * v;
}
static __device__ __forceinline__ float dot4(float4 a, float4 b) {
    return a.x * b.x + a.y * b.y + a.z * b.z + a.w * b.w;
}
static __device__ __forceinline__ unsigned bf16_rne(float x) {
    unsigned u = __builtin_bit_cast(unsigned, x);
    return (u + 0x7FFFu + ((u >> 16) & 1u)) >> 16;
}
static __device__ __forceinline__ void split2(float x, short& hi, short& lo) {
    unsigned h = bf16_rne(x);
    float fh = __builtin_bit_cast(float, h << 16);
    hi = (short)h;
    lo = (short)bf16_rne(x - fh);
}

// ---------------------------------------------------------------------------
// K_PRE: blocks 0..319:  A'[i,o] = S[i].W1[o,0:640] + b1[o]
//                        B'[i,o] = S[i].W1[o,640:1280]
//        blocks 320..719: split W2 -> whi/wlo bf16
//        block 0 / tid 0: reset the producer-done counter (visible to k_main
//        via the kernel-boundary implicit fence; deterministic every replay).
__global__ __launch_bounds__(256) void k_pre(const float* __restrict__ S,
                                             const float* __restrict__ W1,
                                             const float* __restrict__ b1,
                                             const float* __restrict__ W2,
                                             float* __restrict__ A,
                                             float* __restrict__ B,
                                             unsigned short* __restrict__ whi,
                                             unsigned short* __restrict__ wlo,
                                             int* __restrict__ cnt) {
    const int bx = blockIdx.x;
    const int tid = threadIdx.x;
    if (bx == 0 && tid == 0) *cnt = 0;
    if (bx < 320) {
        __shared__ float4 shS[32][33];
        __shared__ float red1[128];
        const int half = bx / 160;
        const int o0   = (bx % 160) * 4;
        const int i  = tid & 31;
        const int ol = (tid >> 5) & 3;
        const int fh = tid >> 7;
        const float4* Wrow = (const float4*)(W1 + (o0 + ol) * (2 * FEAT) + half * FEAT);
        float acc = 0.0f;
        for (int f0 = 0; f0 < FEAT; f0 += 128) {
            __syncthreads();
#pragma unroll
            for (int s = 0; s < 4; ++s) {
                int flat = tid + 256 * s;
                int si = flat >> 5, sf = flat & 31;
                shS[si][sf] = *(const float4*)(S + si * FEAT + f0 + 4 * sf);
            }
            __syncthreads();
            const int kb = (f0 >> 2) + fh * 16;
#pragma unroll
            for (int k = 0; k < 16; ++k)
                acc += dot4(shS[i][fh * 16 + k], Wrow[kb + k]);
        }
        if (fh) red1[tid & 127] = acc;
        __syncthreads();
        if (!fh) {
            float tot = acc + red1[tid & 127];
            if (half == 0) A[i * FEAT + o0 + ol] = tot + b1[o0 + ol];
            else           B[i * FEAT + o0 + ol] = tot;
        }
    } else {
        int e = (bx - 320) * 1024 + tid * 4;
        float4 w = *(const float4*)(W2 + e);
        short h0, l0, h1, l1, h2, l2, h3, l3;
        split2(w.x, h0, l0); split2(w.y, h1, l1);
        split2(w.z, h2, l2); split2(w.w, h3, l3);
        *(short4v*)(whi + e) = (short4v){h0, h1, h2, h3};
        *(short4v*)(wlo + e) = (short4v){l0, l1, l2, l3};
    }
}

// ---------------------------------------------------------------------------
// K_MAIN (producer-consumer fusion, 822 blocks, all co-resident at 4 blk/CU):
//  blocks 0..309   : R5 k3 — bf16x3 MFMA GEMM (BK=32, dbuf, one barrier/step),
//                    colsum epilogue -> part[pt][2][640]; then threadfence +
//                    release atomicAdd on cnt.
//  blocks 310..821 : spin (tid0, s_sleep) until cnt==310, then R6 k5 —
//                    in-register VMG from part+S, 7 independent mfma chains,
//                    alpha folded via ones-frag, out = -sqrt(d2).
// ---------------------------------------------------------------------------
__global__ __launch_bounds__(256, 4) void k_main(const float* __restrict__ Ap,
                                                 const float* __restrict__ Bp,
                                                 const unsigned short* __restrict__ whi,
                                                 const unsigned short* __restrict__ wlo,
                                                 const float* __restrict__ b2,
                                                 const float* __restrict__ S,
                                                 const float* __restrict__ Q,
                                                 float* __restrict__ part,
                                                 int* __restrict__ cnt,
                                                 float* __restrict__ out) {
    __shared__ __align__(16) char smem[24576];
    const int bx  = blockIdx.x;
    const int tid = threadIdx.x;
    const int w    = tid >> 6;
    const int lane = tid & 63;
    const int l15 = lane & 15, l4 = lane >> 4;

    if (bx < NPROD) {
        // ======================= producer: k3 =======================
        struct K3S {
            short lsA[2][2][4][32][8];   // [buf][hi/lo][kc][prow][8]
            short lsB[2][2][4][64][8];   // [buf][hi/lo][kc][orow][8]
        };
        K3S& sm = *reinterpret_cast<K3S*>(smem);
        const int pt = bx % 31;
        const int p0 = pt * 32;
        const int o0 = (bx / 31) * 64;

        const int ar  = tid >> 3;
        const int ac4 = (tid & 7) << 2;
        const int akc = ac4 >> 3;
        const int aof = ac4 & 7;
        const int p = p0 + ar;
        const int ia = p / 31;
        const int jj = p % 31;
        const int ja = jj + (jj >= ia ? 1 : 0);
        const float* Arow = Ap + ia * FEAT;   // b1 folded in
        const float* Brow = Bp + ja * FEAT;
        const int br = tid >> 2;
        const int bk = tid & 3;
        const unsigned short* Whr = whi + (size_t)(o0 + br) * FEAT;
        const unsigned short* Wlr = wlo + (size_t)(o0 + br) * FEAT;

        float4 ra, rb;
        bf16x8 rwh, rwl;
        ra  = *(const float4*)(Arow + ac4);
        rb  = *(const float4*)(Brow + ac4);
        rwh = *(const bf16x8*)(Whr + bk * 8);
        rwl = *(const bf16x8*)(Wlr + bk * 8);

        f32x4 acc[2] = {};

        for (int t = 0; t < FEAT / 32; ++t) {
            const int buf = t & 1;
            {
                float h[4];
                h[0] = leaky(ra.x + rb.x);
                h[1] = leaky(ra.y + rb.y);
                h[2] = leaky(ra.z + rb.z);
                h[3] = leaky(ra.w + rb.w);
                short hi[4], lo[4];
#pragma unroll
                for (int j = 0; j < 4; ++j) split2(h[j], hi[j], lo[j]);
                *(short4v*)&sm.lsA[buf][0][akc][ar][aof] = (short4v){hi[0], hi[1], hi[2], hi[3]};
                *(short4v*)&sm.lsA[buf][1][akc][ar][aof] = (short4v){lo[0], lo[1], lo[2], lo[3]};
                *(bf16x8*)&sm.lsB[buf][0][bk][br][0] = rwh;
                *(bf16x8*)&sm.lsB[buf][1][bk][br][0] = rwl;
            }
            __syncthreads();
            if (t < FEAT / 32 - 1) {
                const int f0 = (t + 1) * 32;
                ra  = *(const float4*)(Arow + f0 + ac4);
                rb  = *(const float4*)(Brow + f0 + ac4);
                rwh = *(const bf16x8*)(Whr + f0 + bk * 8);
                rwl = *(const bf16x8*)(Wlr + f0 + bk * 8);
            }
            bf16x8 ah[2], al[2], bh, bl;
#pragma unroll
            for (int rt = 0; rt < 2; ++rt) {
                ah[rt] = *(const bf16x8*)&sm.lsA[buf][0][l4][rt * 16 + l15][0];
                al[rt] = *(const bf16x8*)&sm.lsA[buf][1][l4][rt * 16 + l15][0];
            }
            bh = *(const bf16x8*)&sm.lsB[buf][0][l4][w * 16 + l15][0];
            bl = *(const bf16x8*)&sm.lsB[buf][1][l4][w * 16 + l15][0];
#pragma unroll
            for (int rt = 0; rt < 2; ++rt) {
                acc[rt] = __builtin_amdgcn_mfma_f32_16x16x32_bf16(ah[rt], bh, acc[rt], 0, 0, 0);
                acc[rt] = __builtin_amdgcn_mfma_f32_16x16x32_bf16(ah[rt], bl, acc[rt], 0, 0, 0);
                acc[rt] = __builtin_amdgcn_mfma_f32_16x16x32_bf16(al[rt], bh, acc[rt], 0, 0, 0);
            }
        }

        // colsum epilogue
        const int oo = o0 + w * 16 + l15;
        const float b2v = b2[oo];
        const int wi0 = p0 / 31;
        const int rsplit = (wi0 + 1) * 31 - p0;
        float s0 = 0.0f, s1 = 0.0f;
#pragma unroll
        for (int r = 0; r < 4; ++r) {
            float v = leaky(acc[0][r] + b2v);
            if (l4 * 4 + r < rsplit) s0 += v; else s1 += v;
            v = leaky(acc[1][r] + b2v);
            if (16 + l4 * 4 + r < rsplit) s0 += v; else s1 += v;
        }
        s0 += __shfl_xor(s0, 16, 64);
        s0 += __shfl_xor(s0, 32, 64);
        s1 += __shfl_xor(s1, 16, 64);
        s1 += __shfl_xor(s1, 32, 64);
        if (l4 == 0) {
            part[(pt * 2 + 0) * FEAT + oo] = s0;
            part[(pt * 2 + 1) * FEAT + oo] = s1;
        }
        __syncthreads();            // all waves' part stores drained (vmcnt)
        if (tid == 0) {
            __threadfence();        // flush to device scope (R9-proven)
            __hip_atomic_fetch_add(cnt, 1, __ATOMIC_RELEASE, __HIP_MEMORY_SCOPE_AGENT);
        }
    } else {
        // ======================= consumer: k5 =======================
        if (tid == 0) {
            while (__hip_atomic_load(cnt, __ATOMIC_ACQUIRE, __HIP_MEMORY_SCOPE_AGENT) < NPROD)
                __builtin_amdgcn_s_sleep(32);
            __threadfence();        // invalidate stale lines (R9-proven)
        }
        __syncthreads();

        float (&red)[4][16][16] = *reinterpret_cast<float (*)[4][16][16]>(smem);
        const int cb = bx - NPROD;
        const int q0 = (cb >> 1) * 16;
        const int by = cb & 1;
        const float* Qrow = Q + (size_t)(q0 + l15) * FEAT + l4 * 8;
        const int wi = by * 16 + l15;
        const int pa = (31 * wi) >> 5;
        const int pb = (31 * wi + 30) >> 5;
        const int ha = wi - (32 * pa) / 31;
        const int hb = wi - (32 * pb) / 31;
        const float du = (pa != pb) ? 1.0f : 0.0f;
        const float* pAr = part + (size_t)(pa * 2 + ha) * FEAT + l4 * 8;
        const float* pBr = part + (size_t)(pb * 2 + hb) * FEAT + l4 * 8;
        const float* Srow = S + (size_t)wi * FEAT + l4 * 8;

        bf16x8 ones;
#pragma unroll
        for (int j = 0; j < 8; ++j) ones[j] = (short)0x3F80;

        f32x4 c0 = {}, c1 = {}, c2 = {}, c3 = {}, c4 = {}, c5 = {}, c6 = {};

        for (int s = 0; s < 5; ++s) {
            const int k0 = w * 160 + s * 32;
            float4 qa = *(const float4*)(Qrow + k0);
            float4 qb = *(const float4*)(Qrow + k0 + 4);
            float qs[8] = {qa.x, qa.y, qa.z, qa.w, qb.x, qb.y, qb.z, qb.w};
            bf16x8 qh, ql, q2h;
#pragma unroll
            for (int j = 0; j < 8; ++j) {
                short h, l;
                split2(qs[j], h, l);
                qh[j] = h; ql[j] = l;
                q2h[j] = (short)bf16_rne(qs[j] * qs[j]);
            }
            float4 ca0 = *(const float4*)(pAr + k0);
            float4 ca1 = *(const float4*)(pAr + k0 + 4);
            float4 cb0 = *(const float4*)(pBr + k0);
            float4 cb1 = *(const float4*)(pBr + k0 + 4);
            float4 sv0 = *(const float4*)(Srow + k0);
            float4 sv1 = *(const float4*)(Srow + k0 + 4);
            float cs[8]  = {ca0.x + du * cb0.x, ca0.y + du * cb0.y,
                            ca0.z + du * cb0.z, ca0.w + du * cb0.w,
                            ca1.x + du * cb1.x, ca1.y + du * cb1.y,
                            ca1.z + du * cb1.z, ca1.w + du * cb1.w};
            float svv[8] = {sv0.x, sv0.y, sv0.z, sv0.w, sv1.x, sv1.y, sv1.z, sv1.w};
            bf16x8 vh, vl, mh, ml, gh, gl;
#pragma unroll
            for (int j = 0; j < 8; ++j) {
                float c1f = cs[j] * (1.0f / 31.0f);
                float c2f = c1f * c1f;
                float m   = c2f * c2f;
                float sv  = svv[j];
                short h, l;
                split2(-2.0f * m * sv, h, l); vh[j] = h; vl[j] = l;
                split2(m, h, l);              mh[j] = h; ml[j] = l;
                split2(m * sv * sv, h, l);    gh[j] = h; gl[j] = l;
            }
            c0 = __builtin_amdgcn_mfma_f32_16x16x32_bf16(qh,   vh, c0, 0, 0, 0);
            c1 = __builtin_amdgcn_mfma_f32_16x16x32_bf16(ql,   vh, c1, 0, 0, 0);
            c2 = __builtin_amdgcn_mfma_f32_16x16x32_bf16(qh,   vl, c2, 0, 0, 0);
            c3 = __builtin_amdgcn_mfma_f32_16x16x32_bf16(q2h,  mh, c3, 0, 0, 0);
            c4 = __builtin_amdgcn_mfma_f32_16x16x32_bf16(q2h,  ml, c4, 0, 0, 0);
            c5 = __builtin_amdgcn_mfma_f32_16x16x32_bf16(ones, gh, c5, 0, 0, 0);
            c6 = __builtin_amdgcn_mfma_f32_16x16x32_bf16(ones, gl, c6, 0, 0, 0);
        }

        f32x4 acc = ((c0 + c1) + (c2 + c3)) + ((c4 + c5) + c6);
#pragma unroll
        for (int r = 0; r < 4; ++r)
            red[w][l4 * 4 + r][l15] = acc[r];
        __syncthreads();

        {
            const int qs_ = tid >> 4, wl = tid & 15;
            float v = red[0][qs_][wl] + red[1][qs_][wl] + red[2][qs_][wl] + red[3][qs_][wl];
            out[(q0 + qs_) * WAY + by * 16 + wl] = -sqrtf(fmaxf(v, 0.0f));
        }
    }
}

extern "C" void kernel_launch(void* const* d_in, const int* in_sizes, int n_in,
                              void* d_out, int out_size, void* d_ws, size_t ws_size,
                              hipStream_t stream) {
    const float* S  = (const float*)d_in[0];   // [32, 640]
    const float* Q  = (const float*)d_in[1];   // [4096, 640]
    const float* W1 = (const float*)d_in[2];   // [640, 1280]
    const float* b1 = (const float*)d_in[3];   // [640]
    const float* W2 = (const float*)d_in[4];   // [640, 640]
    const float* b2 = (const float*)d_in[5];   // [640]
    float* out = (float*)d_out;                // [4096, 32]

    char* wsb = (char*)d_ws;
    float* A    = (float*)wsb;                               // 32*640 f32
    float* B    = A + WAY * FEAT;                            // 32*640 f32
    float* part = B + WAY * FEAT;                            // 31*2*640 f32
    unsigned short* whi = (unsigned short*)(part + 31 * 2 * FEAT);  // 640*640 u16
    unsigned short* wlo = whi + FEAT * FEAT;                 // 640*640 u16
    int* cnt = (int*)(wlo + FEAT * FEAT);                    // 1 int (own line)
    (void)ws_size; (void)in_sizes; (void)n_in; (void)out_size;

    k_pre<<<dim3(720), dim3(256), 0, stream>>>(S, W1, b1, W2, A, B, whi, wlo, cnt);
    k_main<<<dim3(NPROD + NCONS), dim3(256), 0, stream>>>(A, B, whi, wlo, b2, S, Q,
                                                          part, cnt, out);
}

// Round 12
// 46.360 us; speedup vs baseline: 4.0770x; 4.0770x over previous
//
#include <hip/hip_runtime.h>
#include <math.h>

#define WAY   32
#define QUERY 128
#define FEAT  640
#define NPAIR 992
#define WQ    4096

typedef short bf16x8  __attribute__((ext_vector_type(8)));
typedef short short4v __attribute__((ext_vector_type(4)));
typedef float f32x4   __attribute__((ext_vector_type(4)));

static __device__ __forceinline__ float leaky(float v) {
    return v >= 0.0f ? v : 0.2f * v;
}
static __device__ __forceinline__ float dot4(float4 a, float4 b) {
    return a.x * b.x + a.y * b.y + a.z * b.z + a.w * b.w;
}
static __device__ __forceinline__ unsigned bf16_rne(float x) {
    unsigned u = __builtin_bit_cast(unsigned, x);
    return (u + 0x7FFFu + ((u >> 16) & 1u)) >> 16;
}
static __device__ __forceinline__ void split2(float x, short& hi, short& lo) {
    unsigned h = bf16_rne(x);
    float fh = __builtin_bit_cast(float, h << 16);
    hi = (short)h;
    lo = (short)bf16_rne(x - fh);
}

// ---------------------------------------------------------------------------
// K_PRE (R5 exact): blocks 0..319:  A'[i,o] = S[i].W1[o,0:640] + b1[o]
//                                   B'[i,o] = S[i].W1[o,640:1280]
//                   blocks 320..719: split W2 -> whi/wlo bf16
__global__ __launch_bounds__(256) void k_pre(const float* __restrict__ S,
                                             const float* __restrict__ W1,
                                             const float* __restrict__ b1,
                                             const float* __restrict__ W2,
                                             float* __restrict__ A,
                                             float* __restrict__ B,
                                             unsigned short* __restrict__ whi,
                                             unsigned short* __restrict__ wlo) {
    const int bx = blockIdx.x;
    const int tid = threadIdx.x;
    if (bx < 320) {
        __shared__ float4 shS[32][33];
        __shared__ float red1[128];
        const int half = bx / 160;
        const int o0   = (bx % 160) * 4;
        const int i  = tid & 31;
        const int ol = (tid >> 5) & 3;
        const int fh = tid >> 7;
        const float4* Wrow = (const float4*)(W1 + (o0 + ol) * (2 * FEAT) + half * FEAT);
        float acc = 0.0f;
        for (int f0 = 0; f0 < FEAT; f0 += 128) {
            __syncthreads();
#pragma unroll
            for (int s = 0; s < 4; ++s) {
                int flat = tid + 256 * s;
                int si = flat >> 5, sf = flat & 31;
                shS[si][sf] = *(const float4*)(S + si * FEAT + f0 + 4 * sf);
            }
            __syncthreads();
            const int kb = (f0 >> 2) + fh * 16;
#pragma unroll
            for (int k = 0; k < 16; ++k)
                acc += dot4(shS[i][fh * 16 + k], Wrow[kb + k]);
        }
        if (fh) red1[tid & 127] = acc;
        __syncthreads();
        if (!fh) {
            float tot = acc + red1[tid & 127];
            if (half == 0) A[i * FEAT + o0 + ol] = tot + b1[o0 + ol];
            else           B[i * FEAT + o0 + ol] = tot;
        }
    } else {
        int e = (bx - 320) * 1024 + tid * 4;
        float4 w = *(const float4*)(W2 + e);
        short h0, l0, h1, l1, h2, l2, h3, l3;
        split2(w.x, h0, l0); split2(w.y, h1, l1);
        split2(w.z, h2, l2); split2(w.w, h3, l3);
        *(short4v*)(whi + e) = (short4v){h0, h1, h2, h3};
        *(short4v*)(wlo + e) = (short4v){l0, l1, l2, l3};
    }
}

// ---------------------------------------------------------------------------
// K3 v5: identical math/pipeline to R5's k3 (BK=32, dbuf LDS, one barrier per
// step, h2 store) but tile 32p x 32o, 128 threads (2 waves), grid 31 x 20 =
// 620 blocks = 2.4 blocks/CU -> two blocks per CU interleave barrier stalls.
__global__ __launch_bounds__(128) void k3_mfma(const float* __restrict__ Ap,
                                               const float* __restrict__ Bp,
                                               const unsigned short* __restrict__ whi,
                                               const unsigned short* __restrict__ wlo,
                                               const float* __restrict__ b2,
                                               float* __restrict__ h2) {
    __shared__ __align__(16) short lsA[2][2][4][32][8];  // [buf][hi/lo][kc][prow][8]
    __shared__ __align__(16) short lsB[2][2][4][32][8];  // [buf][hi/lo][kc][orow][8]
    const int p0 = blockIdx.x * 32;
    const int o0 = blockIdx.y * 32;
    const int tid = threadIdx.x;
    const int w    = tid >> 6;          // 0..1 -> o-half of 16
    const int lane = tid & 63;
    const int l15 = lane & 15, l4 = lane >> 4;

    // A-staging: 32 rows x 32 k = 256 float4, 2 per thread
    int ar[2], ac4[2], akc[2], aof[2];
#pragma unroll
    for (int s = 0; s < 2; ++s) {
        int flat = tid + 128 * s;
        ar[s]  = flat >> 3;
        ac4[s] = (flat & 7) << 2;
        akc[s] = ac4[s] >> 3;
        aof[s] = ac4[s] & 7;
    }
    const float* Arow[2];
    const float* Brow[2];
#pragma unroll
    for (int s = 0; s < 2; ++s) {
        const int p = p0 + ar[s];
        const int ia = p / 31;
        const int jj = p % 31;
        const int ja = jj + (jj >= ia ? 1 : 0);
        Arow[s] = Ap + ia * FEAT;   // b1 folded in
        Brow[s] = Bp + ja * FEAT;
    }
    // B-staging: 32 rows x 4 kc = 128 bf16x8 per polarity, 1 per thread
    const int br = tid >> 2;
    const int bk = tid & 3;
    const unsigned short* Whr = whi + (size_t)(o0 + br) * FEAT;
    const unsigned short* Wlr = wlo + (size_t)(o0 + br) * FEAT;

    float4 ra[2], rb[2];
    bf16x8 rwh, rwl;
#pragma unroll
    for (int s = 0; s < 2; ++s) {
        ra[s] = *(const float4*)(Arow[s] + ac4[s]);
        rb[s] = *(const float4*)(Brow[s] + ac4[s]);
    }
    rwh = *(const bf16x8*)(Whr + bk * 8);
    rwl = *(const bf16x8*)(Wlr + bk * 8);

    f32x4 acc[2] = {};   // [rt] two 16-row p-halves; wave's 16-o column

    for (int t = 0; t < FEAT / 32; ++t) {
        const int buf = t & 1;
        // ---- write phase (regs of step t)
#pragma unroll
        for (int s = 0; s < 2; ++s) {
            float h[4];
            h[0] = leaky(ra[s].x + rb[s].x);
            h[1] = leaky(ra[s].y + rb[s].y);
            h[2] = leaky(ra[s].z + rb[s].z);
            h[3] = leaky(ra[s].w + rb[s].w);
            short hi[4], lo[4];
#pragma unroll
            for (int j = 0; j < 4; ++j) split2(h[j], hi[j], lo[j]);
            *(short4v*)&lsA[buf][0][akc[s]][ar[s]][aof[s]] = (short4v){hi[0], hi[1], hi[2], hi[3]};
            *(short4v*)&lsA[buf][1][akc[s]][ar[s]][aof[s]] = (short4v){lo[0], lo[1], lo[2], lo[3]};
        }
        *(bf16x8*)&lsB[buf][0][bk][br][0] = rwh;
        *(bf16x8*)&lsB[buf][1][bk][br][0] = rwl;
        __syncthreads();
        // ---- prefetch t+1 (overlaps compute below)
        if (t < FEAT / 32 - 1) {
            const int f0 = (t + 1) * 32;
#pragma unroll
            for (int s = 0; s < 2; ++s) {
                ra[s] = *(const float4*)(Arow[s] + f0 + ac4[s]);
                rb[s] = *(const float4*)(Brow[s] + f0 + ac4[s]);
            }
            rwh = *(const bf16x8*)(Whr + f0 + bk * 8);
            rwl = *(const bf16x8*)(Wlr + f0 + bk * 8);
        }
        // ---- compute: 6 mfma, 2 independent 3-chains
        bf16x8 bh = *(const bf16x8*)&lsB[buf][0][l4][w * 16 + l15][0];
        bf16x8 bl = *(const bf16x8*)&lsB[buf][1][l4][w * 16 + l15][0];
#pragma unroll
        for (int rt = 0; rt < 2; ++rt) {
            bf16x8 ah = *(const bf16x8*)&lsA[buf][0][l4][rt * 16 + l15][0];
            bf16x8 al = *(const bf16x8*)&lsA[buf][1][l4][rt * 16 + l15][0];
            acc[rt] = __builtin_amdgcn_mfma_f32_16x16x32_bf16(ah, bh, acc[rt], 0, 0, 0);
            acc[rt] = __builtin_amdgcn_mfma_f32_16x16x32_bf16(ah, bl, acc[rt], 0, 0, 0);
            acc[rt] = __builtin_amdgcn_mfma_f32_16x16x32_bf16(al, bh, acc[rt], 0, 0, 0);
        }
    }

    // ---- epilogue (R5 layout): C/D col=lane&15, row=(lane>>4)*4+reg
    const int oo = o0 + w * 16 + l15;
    const float b2v = b2[oo];
#pragma unroll
    for (int rt = 0; rt < 2; ++rt)
#pragma unroll
        for (int r = 0; r < 4; ++r) {
            const int pp = p0 + rt * 16 + l4 * 4 + r;
            h2[pp * FEAT + oo] = leaky(acc[rt][r] + b2v);
        }
}

// ---------------------------------------------------------------------------
// K4 (R5 exact): per wi (32 blocks x 640 thr): c1 = mean_jj h2; m = c1^4;
//     V = -2*m*S (bf16 hi/lo), M = m (bf16 hi/lo); alpha via shuffle+LDS.
__global__ __launch_bounds__(640) void k4_ctx(const float* __restrict__ h2,
                                              const float* __restrict__ S,
                                              unsigned short* __restrict__ Vhi,
                                              unsigned short* __restrict__ Vlo,
                                              unsigned short* __restrict__ Mhi,
                                              unsigned short* __restrict__ Mlo,
                                              float* __restrict__ alpha) {
    __shared__ float red[10];
    const int wi = blockIdx.x;
    const int o  = threadIdx.x;
    float s = 0.0f;
#pragma unroll 31
    for (int jj = 0; jj < 31; ++jj)
        s += h2[(wi * 31 + jj) * FEAT + o];
    float c1 = s * (1.0f / 31.0f);
    float c2 = c1 * c1;
    float m  = c2 * c2;
    float sv = S[wi * FEAT + o];
    float vm = -2.0f * m * sv;
    short h, l;
    split2(vm, h, l);
    Vhi[wi * FEAT + o] = (unsigned short)h;
    Vlo[wi * FEAT + o] = (unsigned short)l;
    split2(m, h, l);
    Mhi[wi * FEAT + o] = (unsigned short)h;
    Mlo[wi * FEAT + o] = (unsigned short)l;

    float part = m * sv * sv;
#pragma unroll
    for (int off = 32; off > 0; off >>= 1)
        part += __shfl_down(part, off, 64);
    if ((o & 63) == 0) red[o >> 6] = part;
    __syncthreads();
    if (o == 0) {
        float t = 0.0f;
#pragma unroll
        for (int k = 0; k < 10; ++k) t += red[k];
        alpha[wi] = t;
    }
}

// ---------------------------------------------------------------------------
// K5 (R5 exact): out[q,wi] = -sqrt(alpha[wi] + q.V + q^2.M)
// Grid 256(q-tile) x 2(wi-half) = 512 blocks; 4 waves K-split (160 f each).
__global__ __launch_bounds__(256) void k5_mfma(const float* __restrict__ Q,
                                               const unsigned short* __restrict__ Vhi,
                                               const unsigned short* __restrict__ Vlo,
                                               const unsigned short* __restrict__ Mhi,
                                               const unsigned short* __restrict__ Mlo,
                                               const float* __restrict__ alpha,
                                               float* __restrict__ out) {
    __shared__ float red[4][16][16];
    __shared__ float shAl[16];
    const int q0 = blockIdx.x * 16;
    const int by = blockIdx.y;          // wi-half
    const int tid = threadIdx.x;
    const int w    = tid >> 6;
    const int lane = tid & 63;
    const int l15 = lane & 15, l4 = lane >> 4;
    const float* Qrow = Q + (size_t)(q0 + l15) * FEAT + l4 * 8;
    const int wi = by * 16 + l15;
    const unsigned short* vh = Vhi + (size_t)wi * FEAT + l4 * 8;
    const unsigned short* vl = Vlo + (size_t)wi * FEAT + l4 * 8;
    const unsigned short* mh = Mhi + (size_t)wi * FEAT + l4 * 8;
    const unsigned short* ml = Mlo + (size_t)wi * FEAT + l4 * 8;

    f32x4 c0 = {}, c1 = {}, c2 = {}, c3 = {}, c4 = {};

#pragma unroll
    for (int s = 0; s < 5; ++s) {
        const int k0 = w * 160 + s * 32;
        float4 qa = *(const float4*)(Qrow + k0);
        float4 qb = *(const float4*)(Qrow + k0 + 4);
        float qs[8] = {qa.x, qa.y, qa.z, qa.w, qb.x, qb.y, qb.z, qb.w};
        bf16x8 qh, ql, q2h;
#pragma unroll
        for (int j = 0; j < 8; ++j) {
            short h, l;
            split2(qs[j], h, l);
            qh[j] = h; ql[j] = l;
            q2h[j] = (short)bf16_rne(qs[j] * qs[j]);
        }
        bf16x8 fvh = *(const bf16x8*)(vh + k0);
        bf16x8 fvl = *(const bf16x8*)(vl + k0);
        bf16x8 fmh = *(const bf16x8*)(mh + k0);
        bf16x8 fml = *(const bf16x8*)(ml + k0);
        c0 = __builtin_amdgcn_mfma_f32_16x16x32_bf16(qh,  fvh, c0, 0, 0, 0);
        c1 = __builtin_amdgcn_mfma_f32_16x16x32_bf16(ql,  fvh, c1, 0, 0, 0);
        c2 = __builtin_amdgcn_mfma_f32_16x16x32_bf16(qh,  fvl, c2, 0, 0, 0);
        c3 = __builtin_amdgcn_mfma_f32_16x16x32_bf16(q2h, fmh, c3, 0, 0, 0);
        c4 = __builtin_amdgcn_mfma_f32_16x16x32_bf16(q2h, fml, c4, 0, 0, 0);
    }

    f32x4 acc = c0 + c1 + c2 + c3 + c4;
#pragma unroll
    for (int r = 0; r < 4; ++r)
        red[w][l4 * 4 + r][l15] = acc[r];
    if (tid < 16) shAl[tid] = alpha[by * 16 + tid];
    __syncthreads();

    {
        const int qs_ = tid >> 4, wl = tid & 15;
        float v = red[0][qs_][wl] + red[1][qs_][wl] + red[2][qs_][wl] + red[3][qs_][wl];
        float d2 = shAl[wl] + v;
        out[(q0 + qs_) * WAY + by * 16 + wl] = -sqrtf(fmaxf(d2, 0.0f));
    }
}

extern "C" void kernel_launch(void* const* d_in, const int* in_sizes, int n_in,
                              void* d_out, int out_size, void* d_ws, size_t ws_size,
                              hipStream_t stream) {
    const float* S  = (const float*)d_in[0];   // [32, 640]
    const float* Q  = (const float*)d_in[1];   // [4096, 640]
    const float* W1 = (const float*)d_in[2];   // [640, 1280]
    const float* b1 = (const float*)d_in[3];   // [640]
    const float* W2 = (const float*)d_in[4];   // [640, 640]
    const float* b2 = (const float*)d_in[5];   // [640]
    float* out = (float*)d_out;                // [4096, 32]

    char* wsb = (char*)d_ws;
    float* A     = (float*)wsb;                                 // 32*640 f32
    float* B     = A + WAY * FEAT;                              // 32*640 f32
    float* h2    = B + WAY * FEAT;                              // 992*640 f32
    float* alpha = h2 + NPAIR * FEAT;                           // 32 f32 (+pad)
    unsigned short* whi = (unsigned short*)(alpha + 64);        // 640*640 u16
    unsigned short* wlo = whi + FEAT * FEAT;                    // 640*640 u16
    unsigned short* Vhi = wlo + FEAT * FEAT;                    // 32*640 u16 each
    unsigned short* Vlo = Vhi + WAY * FEAT;
    unsigned short* Mhi = Vlo + WAY * FEAT;
    unsigned short* Mlo = Mhi + WAY * FEAT;
    (void)ws_size; (void)in_sizes; (void)n_in; (void)out_size;

    k_pre<<<dim3(720), dim3(256), 0, stream>>>(S, W1, b1, W2, A, B, whi, wlo);
    k3_mfma<<<dim3(31, 20), dim3(128), 0, stream>>>(A, B, whi, wlo, b2, h2);
    k4_ctx<<<dim3(WAY), dim3(640), 0, stream>>>(h2, S, Vhi, Vlo, Mhi, Mlo, alpha);
    k5_mfma<<<dim3(WQ / 16, 2), dim3(256), 0, stream>>>(Q, Vhi, Vlo, Mhi, Mlo, alpha, out);
}